// Round 6
// baseline (269.458 us; speedup 1.0000x reference)
//
#include <hip/hip_runtime.h>

// out[z,k] = sum_{i,j} C[k,i,j] * f1[z,i] * f2[z,j]
// Z=4096, K=3600, I=J=60, fp32.
//
// Round 6: store-efficiency redesign. Each thread owns 4 consecutive k
// (one k-quad) -> dwordx4 stores, 1KB contiguous per wave-instruction
// (was 256B -> poor DRAM page locality). A pack kernel pre-bakes per-quad
// CG records zero-padded to the 256-k span's max (d1,d2) shape (wave-uniform
// templates, no divergence; segment boundaries are multiples of 16 so quads
// never straddle) in an SoA layout giving coalesced c-loads, plus a packed
// (i0,j0) byte table that removes the whole in-kernel decode.

#define ZT    8      // z rows per block
#define ZPAD  12     // LDS row stride (floats), 16B-aligned
#define NF    60
#define KTOT  3600
#define NKQ   900    // k-quads
#define BLOCK 256
#define PK_IJ_OFF 403200   // bytes; 28*900*16B of c-records first

typedef float f32x4 __attribute__((ext_vector_type(4)));

struct Seg { short kstart, mul2, dl, d1, d2, ioff, joff, pad; };

__constant__ Seg c_segs[19] = {
  {   0,16,1,1,1, 0, 0,0}, { 256, 8,3,1,3, 0,16,0}, { 640, 4,5,1,5, 0,40,0},
  { 960,16,3,3,1,16, 0,0}, {1344, 8,1,3,3,16,16,0}, {1408, 8,3,3,3,16,16,0},
  {1600, 8,5,3,3,16,16,0}, {1920, 4,3,3,5,16,40,0}, {2016, 4,5,3,5,16,40,0},
  {2176, 4,7,3,5,16,40,0}, {2400,16,5,5,1,40, 0,0}, {2720, 8,3,5,3,40,16,0},
  {2816, 8,5,5,3,40,16,0}, {2976, 8,7,5,3,40,16,0}, {3200, 4,1,5,5,40,40,0},
  {3216, 4,3,5,5,40,40,0}, {3264, 4,5,5,5,40,40,0}, {3344, 4,7,5,5,40,40,0},
  {3456, 4,9,5,5,40,40,0}
};

// Per-256-k-span padded max shapes (span = k>>8).
__constant__ unsigned char c_D1[15] = {1,1,1,3,3,3,3,3,3,5,5,5,5,5,5};
__constant__ unsigned char c_D2[15] = {1,3,5,5,1,3,3,5,5,5,3,3,5,5,5};
__constant__ unsigned char c_shape[15] =
  {0x11,0x13,0x15,0x35,0x31,0x33,0x33,0x35,0x35,0x55,0x53,0x53,0x55,0x55,0x55};
// Balanced wave-jobs: kq0 per (block-row, wave-slot); -1 = idle wave.
// Span costs balanced to ~5640 per row (max +5.5%).
__constant__ short c_jobs[4][4] = {
  {832, 768,   0, 896},
  {704, 512, 384,  -1},
  {448, 576, 320, 256},
  {640, 192, 128,  64}
};

__device__ __forceinline__ void decode_k(int kc, Seg& sg, int& i0, int& j0) {
  int s = 0;
  s += (kc >=  256); s += (kc >=  640); s += (kc >=  960); s += (kc >= 1344);
  s += (kc >= 1408); s += (kc >= 1600); s += (kc >= 1920); s += (kc >= 2016);
  s += (kc >= 2176); s += (kc >= 2400); s += (kc >= 2720); s += (kc >= 2816);
  s += (kc >= 2976); s += (kc >= 3200); s += (kc >= 3216); s += (kc >= 3264);
  s += (kc >= 3344); s += (kc >= 3456);
  sg = c_segs[s];
  const int local = kc - sg.kstart;
  const int uv = local / sg.dl;
  const int u  = uv / sg.mul2;
  const int v  = uv - u * sg.mul2;
  i0 = sg.ioff + u * sg.d1;
  j0 = sg.joff + v * sg.d2;
}

// ---------- pack: one thread per (k, padded-row ii) ----------
__global__ __launch_bounds__(BLOCK) void pack_kernel(
    const float* __restrict__ M, float* __restrict__ pk,
    unsigned char* __restrict__ pij)
{
  const int tid = blockIdx.x * BLOCK + (int)threadIdx.x;
  if (tid >= KTOT * 5) return;
  const int k  = tid / 5;
  const int ii = tid - k * 5;
  Seg sg; int i0, j0;
  decode_k(k, sg, i0, j0);
  const int span = k >> 8;
  const int D1 = c_D1[span], D2 = c_D2[span];
  if (ii == 0) { pij[2*k] = (unsigned char)i0; pij[2*k+1] = (unsigned char)j0; }
  if (ii >= D1) return;
  const int kk = k & 3, kq = k >> 2;
  const float* Mr = M + (size_t)k * (NF * NF) + (size_t)(i0 + ii) * NF + j0;
  for (int jj = 0; jj < D2; ++jj) {
    const float v = (ii < sg.d1 && jj < sg.d2) ? Mr[jj] : 0.f;
    const int p = ii * D2 + jj;
    pk[((size_t)(kk * 7 + (p >> 2)) * NKQ + kq) * 4 + (p & 3)] = v;
  }
}

// ---------- main compute ----------
template<int D1, int D2>
__device__ __forceinline__ void run_span(
    int kq, bool valid, const float* __restrict__ pk,
    const unsigned char* __restrict__ pij,
    const float (&f1s)[NF][ZPAD], const float (&f2s)[NF][ZPAD],
    float* __restrict__ out, int z0)
{
  constexpr int NC4 = (D1 * D2 + 3) / 4;
  const uint2 w = *(const uint2*)(pij + 8 * (size_t)kq);   // 4x (i0,j0) bytes
  f32x4 out4[ZT];
#pragma unroll
  for (int kk = 0; kk < 4; ++kk) {
    const unsigned wb = (kk < 2) ? w.x : w.y;
    const int i0 = (wb >> ((kk & 1) * 16)) & 0xFF;
    const int j0 = (wb >> ((kk & 1) * 16 + 8)) & 0xFF;
    float c[NC4 * 4];
#pragma unroll
    for (int p4 = 0; p4 < NC4; ++p4) {
      f32x4 v = *(const f32x4*)(pk + ((size_t)(kk * 7 + p4) * NKQ + kq) * 4);
      c[4*p4+0] = v[0]; c[4*p4+1] = v[1]; c[4*p4+2] = v[2]; c[4*p4+3] = v[3];
    }
#pragma unroll
    for (int zq = 0; zq < ZT / 4; ++zq) {
      f32x4 a[D1], b[D2];
#pragma unroll
      for (int ii = 0; ii < D1; ++ii) a[ii] = *(const f32x4*)&f1s[i0 + ii][zq * 4];
#pragma unroll
      for (int jj = 0; jj < D2; ++jj) b[jj] = *(const f32x4*)&f2s[j0 + jj][zq * 4];
#pragma unroll
      for (int q = 0; q < 4; ++q) {
        float acc = 0.f;
        if constexpr (D1 <= D2) {
#pragma unroll
          for (int ii = 0; ii < D1; ++ii) {
            float t = c[ii * D2] * b[0][q];
#pragma unroll
            for (int jj = 1; jj < D2; ++jj) t = fmaf(c[ii * D2 + jj], b[jj][q], t);
            acc = fmaf(t, a[ii][q], acc);
          }
        } else {
#pragma unroll
          for (int jj = 0; jj < D2; ++jj) {
            float t = c[jj] * a[0][q];
#pragma unroll
            for (int ii = 1; ii < D1; ++ii) t = fmaf(c[ii * D2 + jj], a[ii][q], t);
            acc = fmaf(t, b[jj][q], acc);
          }
        }
        out4[zq * 4 + q][kk] = acc;
      }
    }
  }
  if (valid) {
    float* op = out + (size_t)z0 * KTOT + 4 * (size_t)kq;
#pragma unroll
    for (int z = 0; z < ZT; ++z)
      __builtin_nontemporal_store(out4[z], (f32x4*)(op + (size_t)z * KTOT));
  }
}

__global__ __launch_bounds__(BLOCK, 4) void tp_kernel(
    const float* __restrict__ f1, const float* __restrict__ f2,
    const float* __restrict__ pk, const unsigned char* __restrict__ pij,
    float* __restrict__ out)
{
  __shared__ __align__(16) float f1s[NF][ZPAD];
  __shared__ __align__(16) float f2s[NF][ZPAD];
  const int z0  = blockIdx.y * ZT;
  const int tid = (int)threadIdx.x;

  // Stage 8x60 tiles, feature-major (one coalesced f32x4 per thread).
  const float* f1p = f1 + (size_t)z0 * NF;
  const float* f2p = f2 + (size_t)z0 * NF;
  for (int t = tid; t < (ZT * NF) / 4; t += BLOCK) {
    f32x4 v1 = *(const f32x4*)(f1p + 4 * t);
    f32x4 v2 = *(const f32x4*)(f2p + 4 * t);
    const int zz = (4 * t) / NF, f0 = (4 * t) % NF;
    f1s[f0+0][zz] = v1[0]; f1s[f0+1][zz] = v1[1];
    f1s[f0+2][zz] = v1[2]; f1s[f0+3][zz] = v1[3];
    f2s[f0+0][zz] = v2[0]; f2s[f0+1][zz] = v2[1];
    f2s[f0+2][zz] = v2[2]; f2s[f0+3][zz] = v2[3];
  }

  const int wv   = tid >> 6;
  const int lane = tid & 63;
  // Rotate wave-slot by (by>>6) so each SIMD sees all 4 spans of its row
  // across its blocks (the 4 blocks a CU gets differ by 64 in blockIdx.y).
  const int slot = (wv + (int)(blockIdx.y >> 6)) & 3;
  const int kq0  = (int)c_jobs[blockIdx.x][slot];

  __syncthreads();
  if (kq0 < 0) return;

  int kq = kq0 + lane;
  const bool valid = kq < NKQ;
  if (!valid) kq = NKQ - 1;

  switch (c_shape[kq0 >> 6]) {
    case 0x11: run_span<1,1>(kq, valid, pk, pij, f1s, f2s, out, z0); break;
    case 0x13: run_span<1,3>(kq, valid, pk, pij, f1s, f2s, out, z0); break;
    case 0x15: run_span<1,5>(kq, valid, pk, pij, f1s, f2s, out, z0); break;
    case 0x31: run_span<3,1>(kq, valid, pk, pij, f1s, f2s, out, z0); break;
    case 0x33: run_span<3,3>(kq, valid, pk, pij, f1s, f2s, out, z0); break;
    case 0x35: run_span<3,5>(kq, valid, pk, pij, f1s, f2s, out, z0); break;
    case 0x53: run_span<5,3>(kq, valid, pk, pij, f1s, f2s, out, z0); break;
    default:   run_span<5,5>(kq, valid, pk, pij, f1s, f2s, out, z0); break;
  }
}

extern "C" void kernel_launch(void* const* d_in, const int* in_sizes, int n_in,
                              void* d_out, int out_size, void* d_ws, size_t ws_size,
                              hipStream_t stream) {
  const float* f1 = (const float*)d_in[0];
  const float* f2 = (const float*)d_in[1];
  const float* M  = (const float*)d_in[2];
  float* out = (float*)d_out;
  float* pk  = (float*)d_ws;                                   // 403,200 B
  unsigned char* pij = (unsigned char*)d_ws + PK_IJ_OFF;       // 7,200 B

  pack_kernel<<<dim3((KTOT * 5 + BLOCK - 1) / BLOCK), dim3(BLOCK), 0, stream>>>(M, pk, pij);

  const int Z = in_sizes[0] / NF;          // 4096
  dim3 grid(4, Z / ZT);                    // 4 x 512
  tp_kernel<<<grid, dim3(BLOCK), 0, stream>>>(f1, f2, pk, pij, out);
}

// Round 7
// 93.139 us; speedup vs baseline: 2.8931x; 2.8931x over previous
//
#include <hip/hip_runtime.h>

// out[z,k] = sum_{i,j} C[k,i,j] * f1[z,i] * f2[z,j]
// Z=4096, K=3600, I=J=60, fp32.
//
// Round 7: k-pair threads (dwordx2 stores, 512B contiguous per wave-instr,
// PLAIN stores), wave = 128 consecutive k = one span with compile-time
// padded (D1,D2) -> no decode, no divergence in the compute kernel.
// Pack kernel pre-bakes a 199 KB span-layout c-table (true-shape padding,
// 2x smaller than round 6's) + 4B/pair (i0,j0) table; both coalesced.
// ZT=32 amortizes c over 32 z. 29 span-jobs balanced over 10 k-blocks.

#define ZT    32
#define ZPAD  36     // 144B rows: 16B-aligned b128, rows spread over banks
#define NF    60
#define KTOT  3600
#define BLOCK 256
#define PK_F32X4 12416            // total c-table f32x4 records
#define PIJ_OFF  (PK_F32X4 * 16)  // 198656 B

typedef float f32x4 __attribute__((ext_vector_type(4)));
typedef float f32x2 __attribute__((ext_vector_type(2)));

struct Seg { short kstart, mul2, dl, d1, d2, ioff, joff, pad; };

__constant__ Seg c_segs[19] = {
  {   0,16,1,1,1, 0, 0,0}, { 256, 8,3,1,3, 0,16,0}, { 640, 4,5,1,5, 0,40,0},
  { 960,16,3,3,1,16, 0,0}, {1344, 8,1,3,3,16,16,0}, {1408, 8,3,3,3,16,16,0},
  {1600, 8,5,3,3,16,16,0}, {1920, 4,3,3,5,16,40,0}, {2016, 4,5,3,5,16,40,0},
  {2176, 4,7,3,5,16,40,0}, {2400,16,5,5,1,40, 0,0}, {2720, 8,3,5,3,40,16,0},
  {2816, 8,5,5,3,40,16,0}, {2976, 8,7,5,3,40,16,0}, {3200, 4,1,5,5,40,40,0},
  {3216, 4,3,5,5,40,40,0}, {3264, 4,5,5,5,40,40,0}, {3344, 4,7,5,5,40,40,0},
  {3456, 4,9,5,5,40,40,0}
};

// Per-128-k span tables (span t = k>>7). Padded max shapes; c-table offsets.
__constant__ short c_off[29] = {
  0,128,256,384,512,640,896,1152,1664,1792,1920,2304,2688,3072,3456,3840,
  4352,4864,5376,6272,6528,6784,7296,7808,8320,8832,9728,10624,11520
};
__constant__ unsigned char c_pd1[29] =
  {1,1,1,1,1,1,1,3,3,3,3,3,3,3,3,3,3,3,5,5,5,5,5,5,5,5,5,5,5};
__constant__ unsigned char c_pd2[29] =
  {1,1,3,3,3,5,5,5,1,1,3,3,3,3,3,5,5,5,5,1,1,3,3,3,3,5,5,5,5};
__constant__ unsigned char c_shape2[29] =
  {9,9,11,11,11,13,13,29,25,25,27,27,27,27,27,29,29,29,45,41,41,43,43,43,43,45,45,45,45};
// Balanced jobs: span id per (k-block, wave-slot); -1 idle. Row costs <=2304.
__constant__ signed char c_jobs2[10][4] = {
  {25,15,-1,-1},{26,16,-1,-1},{27,17,-1,-1},{22,23, 0,-1},{24,18, 1,-1},
  {21, 5, 2,-1},{ 6,11,12,-1},{13,14,19,-1},{20, 7,10,28},{ 3, 4, 8, 9}
};

__device__ __forceinline__ void decode_k(int kc, Seg& sg, int& i0, int& j0) {
  int s = 0;
  s += (kc >=  256); s += (kc >=  640); s += (kc >=  960); s += (kc >= 1344);
  s += (kc >= 1408); s += (kc >= 1600); s += (kc >= 1920); s += (kc >= 2016);
  s += (kc >= 2176); s += (kc >= 2400); s += (kc >= 2720); s += (kc >= 2816);
  s += (kc >= 2976); s += (kc >= 3200); s += (kc >= 3216); s += (kc >= 3264);
  s += (kc >= 3344); s += (kc >= 3456);
  sg = c_segs[s];
  const int local = kc - sg.kstart;
  const int uv = local / sg.dl;
  const int u  = uv / sg.mul2;
  const int v  = uv - u * sg.mul2;
  i0 = sg.ioff + u * sg.d1;
  j0 = sg.joff + v * sg.d2;
}

// ---------------- pack: bake c-table + (i0,j0) table ----------------
__global__ __launch_bounds__(BLOCK) void pack_kernel(
    const float* __restrict__ M, float* __restrict__ pk,
    unsigned char* __restrict__ pij)
{
  const int k = blockIdx.x * BLOCK + (int)threadIdx.x;
  if (k >= 3712) return;                 // 29 spans * 128 k (zero-padded tail)
  const int t  = k >> 7, pl = (k >> 1) & 63, kk = k & 1;
  const int D1p = c_pd1[t], D2p = c_pd2[t];
  const int nc4 = (D1p * D2p + 3) >> 2;
  const int base = (int)c_off[t];
  if (k >= KTOT) {
    pij[2*k] = 0; pij[2*k+1] = 0;
    for (int p4 = 0; p4 < nc4; ++p4)
      *(f32x4*)(pk + 4*(size_t)(base + (p4*2 + kk)*64 + pl)) = f32x4{0,0,0,0};
    return;
  }
  Seg sg; int i0, j0;
  decode_k(k, sg, i0, j0);
  pij[2*k] = (unsigned char)i0; pij[2*k+1] = (unsigned char)j0;
  const float* Mk = M + (size_t)k * (NF * NF);
  for (int p = 0; p < nc4 * 4; ++p) {
    const int ii = p / D2p, jj = p - ii * D2p;
    float v = 0.f;
    if (ii < sg.d1 && jj < sg.d2) v = Mk[(i0 + ii) * NF + j0 + jj];
    pk[4*(size_t)(base + ((p >> 2)*2 + kk)*64 + pl) + (p & 3)] = v;
  }
}

// ---------------- compute ----------------
template<int D1, int D2>
__device__ __forceinline__ void load_pair(float (&ca)[28], float (&cb)[28],
    const float* __restrict__ pk, int t, int lane)
{
  constexpr int NC4 = (D1 * D2 + 3) / 4;
  const int base = (int)c_off[t];
#pragma unroll
  for (int p4 = 0; p4 < NC4; ++p4) {
    f32x4 va = *(const f32x4*)(pk + 4*(size_t)(base + (p4*2 + 0)*64 + lane));
    f32x4 vb = *(const f32x4*)(pk + 4*(size_t)(base + (p4*2 + 1)*64 + lane));
    ca[4*p4+0]=va[0]; ca[4*p4+1]=va[1]; ca[4*p4+2]=va[2]; ca[4*p4+3]=va[3];
    cb[4*p4+0]=vb[0]; cb[4*p4+1]=vb[1]; cb[4*p4+2]=vb[2]; cb[4*p4+3]=vb[3];
  }
}

template<int D1, int D2>
__device__ __forceinline__ float bil(const float (&c)[28],
    const f32x4 (&A)[D1], const f32x4 (&B)[D2], int q)
{
  float acc = 0.f;
  if constexpr (D1 <= D2) {
#pragma unroll
    for (int ii = 0; ii < D1; ++ii) {
      float tt = c[ii * D2] * B[0][q];
#pragma unroll
      for (int jj = 1; jj < D2; ++jj) tt = fmaf(c[ii * D2 + jj], B[jj][q], tt);
      acc = fmaf(tt, A[ii][q], acc);
    }
  } else {
#pragma unroll
    for (int jj = 0; jj < D2; ++jj) {
      float tt = c[jj] * A[0][q];
#pragma unroll
      for (int ii = 1; ii < D1; ++ii) tt = fmaf(c[ii * D2 + jj], A[ii][q], tt);
      acc = fmaf(tt, B[jj][q], acc);
    }
  }
  return acc;
}

template<int D1, int D2>
__device__ void comp_pair(const float (&ca)[28], const float (&cb)[28],
    int i0a, int j0a, int i0b, int j0b,
    const float (&f1s)[NF][ZPAD], const float (&f2s)[NF][ZPAD],
    float* __restrict__ op2, bool valid)   // op2 = out + z0*KTOT + ka
{
#pragma unroll 2
  for (int zc = 0; zc < ZT; zc += 4) {
    f32x4 Aa[D1], Ba[D2], Ab[D1], Bb[D2];
#pragma unroll
    for (int ii = 0; ii < D1; ++ii) {
      Aa[ii] = *(const f32x4*)&f1s[i0a + ii][zc];
      Ab[ii] = *(const f32x4*)&f1s[i0b + ii][zc];
    }
#pragma unroll
    for (int jj = 0; jj < D2; ++jj) {
      Ba[jj] = *(const f32x4*)&f2s[j0a + jj][zc];
      Bb[jj] = *(const f32x4*)&f2s[j0b + jj][zc];
    }
#pragma unroll
    for (int q = 0; q < 4; ++q) {
      f32x2 v;
      v[0] = bil<D1,D2>(ca, Aa, Ba, q);
      v[1] = bil<D1,D2>(cb, Ab, Bb, q);
      if (valid) *(f32x2*)(op2 + (size_t)(zc + q) * KTOT) = v;
    }
  }
}

__global__ __launch_bounds__(BLOCK, 4) void tp_kernel(
    const float* __restrict__ f1, const float* __restrict__ f2,
    const float* __restrict__ pk, const unsigned char* __restrict__ pij,
    float* __restrict__ out)
{
  __shared__ __align__(16) float f1s[NF][ZPAD];
  __shared__ __align__(16) float f2s[NF][ZPAD];
  const int z0  = blockIdx.y * ZT;
  const int tid = (int)threadIdx.x;
  const int wv  = tid >> 6;
  const int lane = tid & 63;

  // (1) Issue coalesced staging loads (480 f32x4 per tile).
  const float* f1p = f1 + (size_t)z0 * NF;
  const float* f2p = f2 + (size_t)z0 * NF;
  f32x4 s1a = *(const f32x4*)(f1p + 4 * tid);
  f32x4 s2a = *(const f32x4*)(f2p + 4 * tid);
  f32x4 s1b, s2b;
  const bool two = tid < (ZT * NF) / 4 - BLOCK;   // 480-256=224
  if (two) {
    s1b = *(const f32x4*)(f1p + 4 * (tid + BLOCK));
    s2b = *(const f32x4*)(f2p + 4 * (tid + BLOCK));
  }

  // (2) Job lookup; issue pij + c loads pre-barrier (latency hidden).
  const int slot = (wv + (int)blockIdx.y) & 3;
  const int job  = (int)c_jobs2[blockIdx.x][slot];
  const int t    = job < 0 ? 0 : job;
  const int shape = c_shape2[t];
  const int p = t * 64 + lane;          // global pair index
  unsigned w = 0;
  float ca[28], cb[28];
  if (job >= 0) {
    w = *(const unsigned*)(pij + 4 * (size_t)p);
    switch (shape) {
      case  9: load_pair<1,1>(ca, cb, pk, t, lane); break;
      case 11: load_pair<1,3>(ca, cb, pk, t, lane); break;
      case 13: load_pair<1,5>(ca, cb, pk, t, lane); break;
      case 25: load_pair<3,1>(ca, cb, pk, t, lane); break;
      case 27: load_pair<3,3>(ca, cb, pk, t, lane); break;
      case 29: load_pair<3,5>(ca, cb, pk, t, lane); break;
      case 41: load_pair<5,1>(ca, cb, pk, t, lane); break;
      case 43: load_pair<5,3>(ca, cb, pk, t, lane); break;
      default: load_pair<5,5>(ca, cb, pk, t, lane); break;
    }
  }

  // (3) Transposed LDS write (feature-major f[feat][z]).
  {
    const int g = 4 * tid, zz = g / NF, f0 = g % NF;
    f1s[f0+0][zz] = s1a[0]; f1s[f0+1][zz] = s1a[1];
    f1s[f0+2][zz] = s1a[2]; f1s[f0+3][zz] = s1a[3];
    f2s[f0+0][zz] = s2a[0]; f2s[f0+1][zz] = s2a[1];
    f2s[f0+2][zz] = s2a[2]; f2s[f0+3][zz] = s2a[3];
    if (two) {
      const int g2 = 4 * (tid + BLOCK), z2 = g2 / NF, f2i = g2 % NF;
      f1s[f2i+0][z2] = s1b[0]; f1s[f2i+1][z2] = s1b[1];
      f1s[f2i+2][z2] = s1b[2]; f1s[f2i+3][z2] = s1b[3];
      f2s[f2i+0][z2] = s2b[0]; f2s[f2i+1][z2] = s2b[1];
      f2s[f2i+2][z2] = s2b[2]; f2s[f2i+3][z2] = s2b[3];
    }
  }
  __syncthreads();
  if (job < 0) return;

  const int ka = 2 * p;
  const bool valid = ka < KTOT;
  const int i0a = w & 255, j0a = (w >> 8) & 255;
  const int i0b = (w >> 16) & 255, j0b = (w >> 24) & 255;
  float* op2 = out + (size_t)z0 * KTOT + ka;

  switch (shape) {
    case  9: comp_pair<1,1>(ca, cb, i0a, j0a, i0b, j0b, f1s, f2s, op2, valid); break;
    case 11: comp_pair<1,3>(ca, cb, i0a, j0a, i0b, j0b, f1s, f2s, op2, valid); break;
    case 13: comp_pair<1,5>(ca, cb, i0a, j0a, i0b, j0b, f1s, f2s, op2, valid); break;
    case 25: comp_pair<3,1>(ca, cb, i0a, j0a, i0b, j0b, f1s, f2s, op2, valid); break;
    case 27: comp_pair<3,3>(ca, cb, i0a, j0a, i0b, j0b, f1s, f2s, op2, valid); break;
    case 29: comp_pair<3,5>(ca, cb, i0a, j0a, i0b, j0b, f1s, f2s, op2, valid); break;
    case 41: comp_pair<5,1>(ca, cb, i0a, j0a, i0b, j0b, f1s, f2s, op2, valid); break;
    case 43: comp_pair<5,3>(ca, cb, i0a, j0a, i0b, j0b, f1s, f2s, op2, valid); break;
    default: comp_pair<5,5>(ca, cb, i0a, j0a, i0b, j0b, f1s, f2s, op2, valid); break;
  }
}

extern "C" void kernel_launch(void* const* d_in, const int* in_sizes, int n_in,
                              void* d_out, int out_size, void* d_ws, size_t ws_size,
                              hipStream_t stream) {
  const float* f1 = (const float*)d_in[0];
  const float* f2 = (const float*)d_in[1];
  const float* M  = (const float*)d_in[2];
  float* out = (float*)d_out;
  float* pk  = (float*)d_ws;                              // 198,656 B
  unsigned char* pij = (unsigned char*)d_ws + PIJ_OFF;    //   7,424 B

  pack_kernel<<<dim3(15), dim3(BLOCK), 0, stream>>>(M, pk, pij);

  const int Z = in_sizes[0] / NF;          // 4096
  dim3 grid(10, Z / ZT);                   // 10 x 128
  tp_kernel<<<grid, dim3(BLOCK), 0, stream>>>(f1, f2, pk, pij, out);
}

// Round 9
// 28.442 us; speedup vs baseline: 9.4739x; 3.2747x over previous
//
#include <hip/hip_runtime.h>

// out[z,k] = sum_{i,j} C[k,i,j] * f1[z,i] * f2[z,j]
// Z=4096, K=3600, I=J=60, fp32.
//
// Round 9: R8 design with the half-offset bug fixed (comp_pair now reads
// LDS at z-index half*32+zc; R8 read 0..31 for both halves while writing
// to z0+half*32 -> half the output was computed from the wrong z rows).
// k-pair threads (f32x2 stores, 512B/wave-instr), wave-job = (128-k span,
// 32-z half), per-span compile-time padded shapes (wave-uniform), 58 jobs
// balanced into 16 block-rows, no VGPR cap, pre-barrier M gather.

#define ZT    64
#define ZPAD  68     // LDS row stride: 16B-aligned b128, rows spread banks
#define NF    60
#define KTOT  3600
#define BLOCK 256
#define NLD   ((ZT * NF) / 4)   // 960 f32x4 per feature tile

typedef float f32x4 __attribute__((ext_vector_type(4)));
typedef float f32x2 __attribute__((ext_vector_type(2)));

struct Seg { short kstart, mul2, dl, d1, d2, ioff, joff, pad; };

__constant__ Seg c_segs[19] = {
  {   0,16,1,1,1, 0, 0,0}, { 256, 8,3,1,3, 0,16,0}, { 640, 4,5,1,5, 0,40,0},
  { 960,16,3,3,1,16, 0,0}, {1344, 8,1,3,3,16,16,0}, {1408, 8,3,3,3,16,16,0},
  {1600, 8,5,3,3,16,16,0}, {1920, 4,3,3,5,16,40,0}, {2016, 4,5,3,5,16,40,0},
  {2176, 4,7,3,5,16,40,0}, {2400,16,5,5,1,40, 0,0}, {2720, 8,3,5,3,40,16,0},
  {2816, 8,5,5,3,40,16,0}, {2976, 8,7,5,3,40,16,0}, {3200, 4,1,5,5,40,40,0},
  {3216, 4,3,5,5,40,40,0}, {3264, 4,5,5,5,40,40,0}, {3344, 4,7,5,5,40,40,0},
  {3456, 4,9,5,5,40,40,0}
};

// Per-128-k span padded shape key (pd1<<3)|pd2, span = k>>7.
__constant__ unsigned char c_shape[29] =
  {9,9,11,11,11,13,13,29,25,25,27,27,27,27,27,29,29,29,45,41,41,43,43,43,43,
   45,45,45,45};
// Balanced job table: job = span*2 + z_half; -1 idle. Row costs <=13 (avg 12).
__constant__ signed char c_jobs[16][4] = {
  {36,37, 4,-1}, {50,51, 5,-1}, {52,53, 6,-1}, {54,55, 7,-1}, {56,57, 8,-1},
  {14,30,31, 0}, {15,32,33, 1}, {34,35,42, 2}, {43,44,45, 3}, {46,47,48,-1},
  {49,10,11, 9}, {12,13,20,21}, {22,23,24,25}, {26,27,28,29}, {38,39,40,41},
  {16,17,18,19}
};

__device__ __forceinline__ void decode_k(int kc, Seg& sg, int& i0, int& j0) {
  int s = 0;
  s += (kc >=  256); s += (kc >=  640); s += (kc >=  960); s += (kc >= 1344);
  s += (kc >= 1408); s += (kc >= 1600); s += (kc >= 1920); s += (kc >= 2016);
  s += (kc >= 2176); s += (kc >= 2400); s += (kc >= 2720); s += (kc >= 2816);
  s += (kc >= 2976); s += (kc >= 3200); s += (kc >= 3216); s += (kc >= 3264);
  s += (kc >= 3344); s += (kc >= 3456);
  sg = c_segs[s];
  const int local = kc - sg.kstart;
  const int uv = local / sg.dl;
  const int u  = uv / sg.mul2;
  const int v  = uv - u * sg.mul2;
  i0 = sg.ioff + u * sg.d1;
  j0 = sg.joff + v * sg.d2;
}

// Gather one k's CG block, padded (D1,D2), true shape (td1,td2) zero-filled.
template<int D1, int D2>
__device__ __forceinline__ void gather_c(float (&c)[25],
    const float* __restrict__ M, int k, int i0, int j0, int td1, int td2)
{
  const float* Mr = M + (size_t)k * (NF * NF) + (size_t)i0 * NF + j0;
#pragma unroll
  for (int ii = 0; ii < D1; ++ii)
#pragma unroll
    for (int jj = 0; jj < D2; ++jj)
      c[ii * D2 + jj] = (ii < td1 && jj < td2) ? Mr[ii * NF + jj] : 0.f;
}

template<int D1, int D2>
__device__ __forceinline__ float bil(const float (&c)[25],
    const f32x4 (&A)[D1], const f32x4 (&B)[D2], int q)
{
  float acc = 0.f;
  if constexpr (D1 <= D2) {
#pragma unroll
    for (int ii = 0; ii < D1; ++ii) {
      float t = c[ii * D2] * B[0][q];
#pragma unroll
      for (int jj = 1; jj < D2; ++jj) t = fmaf(c[ii * D2 + jj], B[jj][q], t);
      acc = fmaf(t, A[ii][q], acc);
    }
  } else {
#pragma unroll
    for (int jj = 0; jj < D2; ++jj) {
      float t = c[jj] * A[0][q];
#pragma unroll
      for (int ii = 1; ii < D1; ++ii) t = fmaf(c[ii * D2 + jj], A[ii][q], t);
      acc = fmaf(t, B[jj][q], acc);
    }
  }
  return acc;
}

template<int D1, int D2>
__device__ void comp_pair(const float (&ca)[25], const float (&cb)[25],
    int i0a, int j0a, int i0b, int j0b, int zb,
    const float (&f1s)[NF][ZPAD], const float (&f2s)[NF][ZPAD],
    float* __restrict__ op, bool valid)   // op = out + (z0+zb)*KTOT + ka
{
#pragma unroll 2
  for (int zc = 0; zc < 32; zc += 4) {
    f32x4 Aa[D1], Ba[D2], Ab[D1], Bb[D2];
#pragma unroll
    for (int ii = 0; ii < D1; ++ii) {
      Aa[ii] = *(const f32x4*)&f1s[i0a + ii][zb + zc];
      Ab[ii] = *(const f32x4*)&f1s[i0b + ii][zb + zc];
    }
#pragma unroll
    for (int jj = 0; jj < D2; ++jj) {
      Ba[jj] = *(const f32x4*)&f2s[j0a + jj][zb + zc];
      Bb[jj] = *(const f32x4*)&f2s[j0b + jj][zb + zc];
    }
#pragma unroll
    for (int q = 0; q < 4; ++q) {
      f32x2 v;
      v[0] = bil<D1,D2>(ca, Aa, Ba, q);
      v[1] = bil<D1,D2>(cb, Ab, Bb, q);
      if (valid) *(f32x2*)(op + (size_t)(zc + q) * KTOT) = v;
    }
  }
}

__global__ __launch_bounds__(BLOCK) void tp_kernel(
    const float* __restrict__ f1, const float* __restrict__ f2,
    const float* __restrict__ M, float* __restrict__ out)
{
  __shared__ __align__(16) float f1s[NF][ZPAD];
  __shared__ __align__(16) float f2s[NF][ZPAD];
  const int z0   = blockIdx.y * ZT;
  const int tid  = (int)threadIdx.x;
  const int wv   = tid >> 6;
  const int lane = tid & 63;

  // (1) Issue coalesced staging loads into registers.
  const float* f1p = f1 + (size_t)z0 * NF;
  const float* f2p = f2 + (size_t)z0 * NF;
  f32x4 s1[4], s2[4];
#pragma unroll
  for (int r = 0; r < 4; ++r) {
    const int t = tid + r * BLOCK;
    if (t < NLD) {
      s1[r] = *(const f32x4*)(f1p + 4 * t);
      s2[r] = *(const f32x4*)(f2p + 4 * t);
    }
  }

  // (2) Job lookup + decode; issue c-gather pre-barrier (latency hidden).
  const int job  = (int)c_jobs[blockIdx.x][(wv + (int)blockIdx.y) & 3];
  const bool wact = job >= 0;
  const int span = wact ? (job >> 1) : 0;
  const int zb   = wact ? (job & 1) * 32 : 0;
  const int ka   = span * 128 + 2 * lane;
  const bool valid = wact && (ka < KTOT);
  const int kca = valid ? ka : 0;
  const int kcb = valid ? ka + 1 : 0;
  Seg sA, sB; int i0a, j0a, i0b, j0b;
  decode_k(kca, sA, i0a, j0a);
  decode_k(kcb, sB, i0b, j0b);
  const int shape = (int)c_shape[span];

  float ca[25], cb[25];
  switch (shape) {
    case  9: gather_c<1,1>(ca,M,kca,i0a,j0a,sA.d1,sA.d2);
             gather_c<1,1>(cb,M,kcb,i0b,j0b,sB.d1,sB.d2); break;
    case 11: gather_c<1,3>(ca,M,kca,i0a,j0a,sA.d1,sA.d2);
             gather_c<1,3>(cb,M,kcb,i0b,j0b,sB.d1,sB.d2); break;
    case 13: gather_c<1,5>(ca,M,kca,i0a,j0a,sA.d1,sA.d2);
             gather_c<1,5>(cb,M,kcb,i0b,j0b,sB.d1,sB.d2); break;
    case 25: gather_c<3,1>(ca,M,kca,i0a,j0a,sA.d1,sA.d2);
             gather_c<3,1>(cb,M,kcb,i0b,j0b,sB.d1,sB.d2); break;
    case 27: gather_c<3,3>(ca,M,kca,i0a,j0a,sA.d1,sA.d2);
             gather_c<3,3>(cb,M,kcb,i0b,j0b,sB.d1,sB.d2); break;
    case 29: gather_c<3,5>(ca,M,kca,i0a,j0a,sA.d1,sA.d2);
             gather_c<3,5>(cb,M,kcb,i0b,j0b,sB.d1,sB.d2); break;
    case 41: gather_c<5,1>(ca,M,kca,i0a,j0a,sA.d1,sA.d2);
             gather_c<5,1>(cb,M,kcb,i0b,j0b,sB.d1,sB.d2); break;
    case 43: gather_c<5,3>(ca,M,kca,i0a,j0a,sA.d1,sA.d2);
             gather_c<5,3>(cb,M,kcb,i0b,j0b,sB.d1,sB.d2); break;
    default: gather_c<5,5>(ca,M,kca,i0a,j0a,sA.d1,sA.d2);
             gather_c<5,5>(cb,M,kcb,i0b,j0b,sB.d1,sB.d2); break;
  }

  // (3) Transposed LDS write (feature-major f[feat][z]).
#pragma unroll
  for (int r = 0; r < 4; ++r) {
    const int t = tid + r * BLOCK;
    if (t < NLD) {
      const int g = 4 * t, zz = g / NF, f0 = g % NF;
      f1s[f0+0][zz] = s1[r][0]; f1s[f0+1][zz] = s1[r][1];
      f1s[f0+2][zz] = s1[r][2]; f1s[f0+3][zz] = s1[r][3];
      f2s[f0+0][zz] = s2[r][0]; f2s[f0+1][zz] = s2[r][1];
      f2s[f0+2][zz] = s2[r][2]; f2s[f0+3][zz] = s2[r][3];
    }
  }
  __syncthreads();
  if (!wact) return;

  float* op = out + (size_t)(z0 + zb) * KTOT + ka;

  switch (shape) {
    case  9: comp_pair<1,1>(ca,cb,i0a,j0a,i0b,j0b,zb,f1s,f2s,op,valid); break;
    case 11: comp_pair<1,3>(ca,cb,i0a,j0a,i0b,j0b,zb,f1s,f2s,op,valid); break;
    case 13: comp_pair<1,5>(ca,cb,i0a,j0a,i0b,j0b,zb,f1s,f2s,op,valid); break;
    case 25: comp_pair<3,1>(ca,cb,i0a,j0a,i0b,j0b,zb,f1s,f2s,op,valid); break;
    case 27: comp_pair<3,3>(ca,cb,i0a,j0a,i0b,j0b,zb,f1s,f2s,op,valid); break;
    case 29: comp_pair<3,5>(ca,cb,i0a,j0a,i0b,j0b,zb,f1s,f2s,op,valid); break;
    case 41: comp_pair<5,1>(ca,cb,i0a,j0a,i0b,j0b,zb,f1s,f2s,op,valid); break;
    case 43: comp_pair<5,3>(ca,cb,i0a,j0a,i0b,j0b,zb,f1s,f2s,op,valid); break;
    default: comp_pair<5,5>(ca,cb,i0a,j0a,i0b,j0b,zb,f1s,f2s,op,valid); break;
  }
}

extern "C" void kernel_launch(void* const* d_in, const int* in_sizes, int n_in,
                              void* d_out, int out_size, void* d_ws, size_t ws_size,
                              hipStream_t stream) {
  const float* f1 = (const float*)d_in[0];
  const float* f2 = (const float*)d_in[1];
  const float* M  = (const float*)d_in[2];
  float* out = (float*)d_out;

  const int Z = in_sizes[0] / NF;          // 4096
  dim3 grid(16, Z / ZT);                   // 16 x 64 = 1024 blocks
  tp_kernel<<<grid, dim3(BLOCK), 0, stream>>>(f1, f2, M, out);
}